// Round 13
// baseline (107.058 us; speedup 1.0000x reference)
//
#include <hip/hip_runtime.h>
#include <stdint.h>

#define NTREES 8
#define NNODES 5
#define CC 16
#define BB 8
#define HH 224
#define WW 224
#define NBAND 56          // 224 / 4 rows per band

struct Forest { int par[NTREES * NNODES]; };
struct Cls { int v[NTREES]; };

// ---------------------------------------------------------------------------
// Host-side bit-exact reproduction of np.random.default_rng(0) forest
// (verified absmax 0.0 vs numpy in rounds 1-12 — do not touch).
// ---------------------------------------------------------------------------
namespace nprng {

struct Pcg {
  __uint128_t state, inc;
  int has_uint32;
  uint32_t uinteger;
};

static inline __uint128_t pcg_mult() {
  return (((__uint128_t)0x2360ED051FC65DA4ULL) << 64) | 0x4385DF649FCCF645ULL;
}

static inline void pcg_step(Pcg& s) { s.state = s.state * pcg_mult() + s.inc; }

static inline uint64_t pcg_next64(Pcg& s) {
  pcg_step(s);
  uint64_t xored = (uint64_t)(s.state >> 64) ^ (uint64_t)s.state;
  unsigned rot = (unsigned)(s.state >> 122);
  return (xored >> rot) | (xored << ((64u - rot) & 63u));
}

static inline uint32_t pcg_next32(Pcg& s) {
  if (s.has_uint32) { s.has_uint32 = 0; return s.uinteger; }
  uint64_t n = pcg_next64(s);
  s.has_uint32 = 1;
  s.uinteger = (uint32_t)(n >> 32);
  return (uint32_t)n;
}

static inline uint32_t lemire32(Pcg& s, uint32_t rng) {
  const uint32_t rng_excl = rng + 1u;
  uint64_t m = (uint64_t)pcg_next32(s) * (uint64_t)rng_excl;
  uint32_t leftover = (uint32_t)m;
  if (leftover < rng_excl) {
    const uint32_t threshold = (uint32_t)((0xFFFFFFFFu - rng) % rng_excl);
    while (leftover < threshold) {
      m = (uint64_t)pcg_next32(s) * (uint64_t)rng_excl;
      leftover = (uint32_t)m;
    }
  }
  return (uint32_t)(m >> 32);
}

static void make_forest(Forest& f) {
  const uint32_t INIT_A = 0x43b0d7e5u, MULT_A = 0x931e8875u;
  const uint32_t INIT_B = 0x8b51f9ddu, MULT_B = 0x58f38dedu;
  const uint32_t MIX_L  = 0xca01f9ddu, MIX_R  = 0x4973f715u;
  uint32_t pool[4];
  uint32_t hc = INIT_A;
  auto hashmix = [&](uint32_t v) -> uint32_t {
    v ^= hc; hc *= MULT_A; v *= hc; v ^= v >> 16; return v;
  };
  auto mix = [&](uint32_t x, uint32_t y) -> uint32_t {
    uint32_t r = MIX_L * x - MIX_R * y; r ^= r >> 16; return r;
  };
  pool[0] = hashmix(0u);
  for (int i = 1; i < 4; ++i) pool[i] = hashmix(0u);
  for (int is = 0; is < 4; ++is)
    for (int id = 0; id < 4; ++id)
      if (is != id) pool[id] = mix(pool[id], hashmix(pool[is]));
  uint32_t st32[8];
  uint32_t hb = INIT_B;
  for (int i = 0; i < 8; ++i) {
    uint32_t dv = pool[i & 3];
    dv ^= hb; hb *= MULT_B; dv *= hb; dv ^= dv >> 16;
    st32[i] = dv;
  }
  uint64_t w64[4];
  for (int i = 0; i < 4; ++i)
    w64[i] = (uint64_t)st32[2 * i] | ((uint64_t)st32[2 * i + 1] << 32);

  __uint128_t initstate = (((__uint128_t)w64[0]) << 64) | w64[1];
  __uint128_t initseq   = (((__uint128_t)w64[2]) << 64) | w64[3];
  Pcg s;
  s.state = 0; s.inc = (initseq << 1) | 1;
  pcg_step(s);
  s.state += initstate;
  pcg_step(s);
  s.has_uint32 = 0; s.uinteger = 0;

  for (int t = 0; t < NTREES; ++t) {
    f.par[t * NNODES + 0] = -1;
    for (int i = 1; i < NNODES; ++i) {
      uint32_t rng = (uint32_t)(i - 1);
      f.par[t * NNODES + i] = (rng == 0) ? 0 : (int)lemire32(s, rng);
    }
  }
}

}  // namespace nprng

// ---------------------------------------------------------------------------
// Tree-shape classification + level-form class configs (verified absmax 0.0
// R8/R10/R11/R12): chain C1 = fv*sL^E1L; C2 = fv*sL^E2L*sC1; C3 = fv*sC2;
// root = fv*sL^RL*sC1^R1*sC2^R2*sC3^R3 (all s at row h-1).
// ---------------------------------------------------------------------------
static int classify_tree(const int* p) {
  int nch[NNODES] = {0, 0, 0, 0, 0};
  for (int i = 1; i < NNODES; ++i) nch[p[i]]++;
  int internals[3], nI = 0;
  for (int i = 1; i <= 3; ++i) if (nch[i] > 0) internals[nI++] = i;
  if (nI == 0) return 1;
  if (nI == 1) {
    int m = nch[internals[0]];
    return m == 1 ? 2 : (m == 2 ? 3 : 4);
  }
  if (nI == 2) {
    int i = internals[0], j = internals[1];
    if (p[j] == i) {
      if (nch[j] == 2) return 9;
      return (nch[i] - 1 == 1) ? 7 : 6;
    }
    return 5;
  }
  return 8;
}

template <int CL> struct TC;
template <> struct TC<1> { static constexpr int H1=0,E1L=0,H2=0,E2L=0,H3=0,RL=4,R1=0,R2=0,R3=0; };
template <> struct TC<2> { static constexpr int H1=1,E1L=1,H2=0,E2L=0,H3=0,RL=2,R1=1,R2=0,R3=0; };
template <> struct TC<3> { static constexpr int H1=1,E1L=2,H2=0,E2L=0,H3=0,RL=1,R1=1,R2=0,R3=0; };
template <> struct TC<4> { static constexpr int H1=1,E1L=3,H2=0,E2L=0,H3=0,RL=0,R1=1,R2=0,R3=0; };
template <> struct TC<5> { static constexpr int H1=1,E1L=1,H2=0,E2L=0,H3=0,RL=0,R1=2,R2=0,R3=0; };
template <> struct TC<6> { static constexpr int H1=1,E1L=1,H2=1,E2L=0,H3=0,RL=1,R1=0,R2=1,R3=0; };
template <> struct TC<7> { static constexpr int H1=1,E1L=1,H2=1,E2L=1,H3=0,RL=0,R1=0,R2=1,R3=0; };
template <> struct TC<8> { static constexpr int H1=1,E1L=1,H2=1,E2L=0,H3=1,RL=0,R1=0,R2=0,R3=1; };
template <> struct TC<9> { static constexpr int H1=1,E1L=2,H2=1,E2L=0,H3=0,RL=0,R1=0,R2=1,R3=0; };

// ---------------------------------------------------------------------------
// DPP helpers (product space, max identity 0.0; patterns verified R4-R12).
// Mega-scans: ALL active levels' row-scans fused into one asm block,
// round-robin interleaved: dependent same-register DPPs are 4N insts apart
// (N = q count per stage group) -> issue-bound, zero latency exposure.
// ---------------------------------------------------------------------------
__device__ __forceinline__ float wshr1(float t) {
  int r = __builtin_amdgcn_update_dpp(
      0, __builtin_bit_cast(int, t), 0x138, 0xf, 0xf, true);  // wave_shr:1
  return __builtin_bit_cast(float, r);
}

#define DPP_S1  "row_shr:1 row_mask:0xf bank_mask:0xf"
#define DPP_S2  "row_shr:2 row_mask:0xf bank_mask:0xf"
#define DPP_S4  "row_shr:4 row_mask:0xf bank_mask:0xf"
#define DPP_S8  "row_shr:8 row_mask:0xf bank_mask:0xf"
#define DPP_B15 "row_bcast:15 row_mask:0xa bank_mask:0xf"
#define DPP_B31 "row_bcast:31 row_mask:0xc bank_mask:0xf"

#define OPROW(n, M) "v_max_f32_dpp %" #n ", %" #n ", %" #n " " M "\n\t"

#define OPS4(M)  OPROW(0,M) OPROW(1,M) OPROW(2,M) OPROW(3,M)
#define OPS8(M)  OPS4(M)  OPROW(4,M) OPROW(5,M) OPROW(6,M) OPROW(7,M)
#define OPS12(M) OPS8(M)  OPROW(8,M) OPROW(9,M) OPROW(10,M) OPROW(11,M)
#define OPS16(M) OPS12(M) OPROW(12,M) OPROW(13,M) OPROW(14,M) OPROW(15,M)

#define SCANBODY(OPS) \
  "s_nop 1\n\t" OPS(DPP_S1) OPS(DPP_S2) OPS(DPP_S4) OPS(DPP_S8) \
  OPS(DPP_B15) OPS(DPP_B31) "s_nop 1"

#define SCAN4Q(q)  asm volatile(SCANBODY(OPS4)  : "+v"((q)[0]), "+v"((q)[1]), "+v"((q)[2]), "+v"((q)[3]))
#define SCAN8Q(q)  asm volatile(SCANBODY(OPS8)  : "+v"((q)[0]), "+v"((q)[1]), "+v"((q)[2]), "+v"((q)[3]), \
                                                  "+v"((q)[4]), "+v"((q)[5]), "+v"((q)[6]), "+v"((q)[7]))
#define SCAN12Q(q) asm volatile(SCANBODY(OPS12) : "+v"((q)[0]), "+v"((q)[1]), "+v"((q)[2]), "+v"((q)[3]), \
                                                  "+v"((q)[4]), "+v"((q)[5]), "+v"((q)[6]), "+v"((q)[7]), \
                                                  "+v"((q)[8]), "+v"((q)[9]), "+v"((q)[10]), "+v"((q)[11]))
#define SCAN16Q(q) asm volatile(SCANBODY(OPS16) : "+v"((q)[0]), "+v"((q)[1]), "+v"((q)[2]), "+v"((q)[3]), \
                                                  "+v"((q)[4]), "+v"((q)[5]), "+v"((q)[6]), "+v"((q)[7]), \
                                                  "+v"((q)[8]), "+v"((q)[9]), "+v"((q)[10]), "+v"((q)[11]), \
                                                  "+v"((q)[12]), "+v"((q)[13]), "+v"((q)[14]), "+v"((q)[15]))

#define MUL4(d, s) { (d).x *= (s).x; (d).y *= (s).y; (d).z *= (s).z; (d).w *= (s).w; }
#define MAX4(d, s) { (d).x = fmaxf((d).x,(s).x); (d).y = fmaxf((d).y,(s).y); \
                     (d).z = fmaxf((d).z,(s).z); (d).w = fmaxf((d).w,(s).w); }

template <int E>
__device__ __forceinline__ void powmul(float4& v, const float4& s) {
  if constexpr (E == 4) {
    float4 t = s; MUL4(t, t); MUL4(t, t); MUL4(v, t);
  } else {
    if constexpr (E >= 1) MUL4(v, s);
    if constexpr (E >= 2) MUL4(v, s);
    if constexpr (E >= 3) MUL4(v, s);
  }
}

// shifted-space source at band row u: u==0 -> previous band's tail.
__device__ __forceinline__ float4 srcat(const float4 S[4], const float4& tail, int u) {
  return (u == 0) ? tail : S[u - 1];
}

struct LocB { float x0[4], l1[4], l2[4]; };

__device__ __forceinline__ void mk_q(const float4 v[4], LocB& L, float* q) {
#pragma unroll
  for (int u = 0; u < 4; ++u) {
    L.x0[u] = v[u].x;
    L.l1[u] = fmaxf(v[u].x, v[u].y);
    L.l2[u] = fmaxf(L.l1[u], v[u].z);
    q[u]    = fmaxf(L.l2[u], v[u].w);
  }
}

// Shifted-space run update (R12-verified formula). tail := old S[3]
// (= S(prev band)[3], consumed by next iteration's u==0 sources).
__device__ __forceinline__ void run_update(const LocB& L, const float* q,
                                           float4 S[4], float4& tail) {
  tail = S[3];
  float4 run = tail;
#pragma unroll
  for (int u = 0; u < 4; ++u) {
    float e = wshr1(q[u]);
    run.x = fmaxf(run.x, e);
    run.y = fmaxf(run.y, fmaxf(e, L.x0[u]));
    run.z = fmaxf(run.z, fmaxf(e, L.l1[u]));
    run.w = fmaxf(run.w, fmaxf(e, L.l2[u]));
    S[u] = run;
  }
}

// ---------------------------------------------------------------------------
// LEVEL-PIPELINED band DP, one wave per (tree,b,c). Product space (exp
// isomorphism, verified R6-R12): f=(1+relu(x))*mask, sentinel 0.0,
// out = exp(asum)*m - 1.
//
// Iteration i computes: leaf(band i), C1(band i-1), C2(band i-2),
// C3(band i-3), root(band i-(D-1)) — mutually independent => one fused
// SCAN(4*D) asm per iteration, breaking R8-R12's serial per-band scan chain.
// Out-of-range bands use fv=0 = exact no-op (values >= 0) => uniform loop,
// no prologue/epilogue. Generation staging: fv x D; SLm1 (one extra SL gen)
// only for classes 6 (root RL) / 7 (E2L); tails = old S[3] per level.
// Within-iteration order (consume-before-overwrite, proven per class):
// v-computes (old S/tails) -> mega-scan -> S3,S2,S1 updates -> root (fresh
// top S, old lower gens) -> SLm1 rotation -> SL update -> (D==1 root) ->
// fv rotations, X<-T.
// ---------------------------------------------------------------------------
template <int CL>
__device__ __forceinline__ void run_tree(const float* __restrict__ cp,
                                         float mask, float asum,
                                         float* __restrict__ outp, int lane) {
  using F = TC<CL>;
  constexpr int D = 1 + F::H1 + F::H2 + F::H3;
  constexpr bool NEEDM1 = (F::H2 != 0) && (F::E2L > 0 || F::RL > 0);
  const float4 z4 = make_float4(0.f, 0.f, 0.f, 0.f);

  float4 SL[4] = {z4, z4, z4, z4}, S1[4] = {z4, z4, z4, z4};
  float4 S2[4] = {z4, z4, z4, z4}, S3[4] = {z4, z4, z4, z4};
  float4 SLm1[4] = {z4, z4, z4, z4};
  float4 tailL = z4, tail1 = z4, tail2 = z4, tail3 = z4, tailLm1 = z4;
  float4 fv1[4] = {z4, z4, z4, z4}, fv2[4] = {z4, z4, z4, z4},
         fv3[4] = {z4, z4, z4, z4};
  float4 racc = z4;

  float4 X[4];
#pragma unroll
  for (int u = 0; u < 4; ++u) X[u] = *(const float4*)(cp + u * WW);

#pragma unroll 1
  for (int i = 0; i < NBAND + D - 1; ++i) {
    // prefetch next band (clamped; consumed next iteration)
    const int nb = (i + 1 < NBAND) ? (i + 1) : (NBAND - 1);
    float4 T[4];
#pragma unroll
    for (int u = 0; u < 4; ++u)
      T[u] = *(const float4*)(cp + (size_t)(nb * 4 + u) * WW);

    // fv for band i (0 for virtual bands i >= NBAND)
    const float bm = (i < NBAND) ? mask : 0.f;
    float4 fv0[4];
#pragma unroll
    for (int u = 0; u < 4; ++u) {
      fv0[u].x = fmaf(fmaxf(X[u].x, 0.f), bm, bm);
      fv0[u].y = fmaf(fmaxf(X[u].y, 0.f), bm, bm);
      fv0[u].z = fmaf(fmaxf(X[u].z, 0.f), bm, bm);
      fv0[u].w = fmaf(fmaxf(X[u].w, 0.f), bm, bm);
    }

    // ---- v-computes for all active levels (consume OLD S gens/tails) ----
    LocB loL, lo1, lo2, lo3;
    float q[16];
    mk_q(fv0, loL, q + 0);  // leaf, band i
    if constexpr (F::H1) {  // C1, band i-1
      float4 v[4];
#pragma unroll
      for (int u = 0; u < 4; ++u) {
        v[u] = fv1[u];
        powmul<F::E1L>(v[u], srcat(SL, tailL, u));
      }
      mk_q(v, lo1, q + 4);
    }
    if constexpr (F::H2) {  // C2, band i-2
      float4 v[4];
#pragma unroll
      for (int u = 0; u < 4; ++u) {
        v[u] = fv2[u];
        if constexpr (F::E2L > 0) powmul<F::E2L>(v[u], srcat(SLm1, tailLm1, u));
        float4 s = srcat(S1, tail1, u);
        MUL4(v[u], s);
      }
      mk_q(v, lo2, q + 8);
    }
    if constexpr (F::H3) {  // C3, band i-3
      float4 v[4];
#pragma unroll
      for (int u = 0; u < 4; ++u) {
        v[u] = fv3[u];
        float4 s = srcat(S2, tail2, u);
        MUL4(v[u], s);
      }
      mk_q(v, lo3, q + 12);
    }

    // ---- one fused scan for all active levels ----
    if constexpr (D == 1)      { SCAN4Q(q); }
    else if constexpr (D == 2) { SCAN8Q(q); }
    else if constexpr (D == 3) { SCAN12Q(q); }
    else                       { SCAN16Q(q); }

    // ---- run updates, top level first (leaf LAST, after root) ----
    if constexpr (F::H3) run_update(lo3, q + 12, S3, tail3);
    if constexpr (F::H2) run_update(lo2, q + 8, S2, tail2);
    if constexpr (F::H1) run_update(lo1, q + 4, S1, tail1);

    // ---- root for band i-(D-1) (fresh top S; older gens for lower) ----
    if constexpr (D > 1) {
#pragma unroll
      for (int u = 0; u < 4; ++u) {
        float4 r;
        if constexpr (D == 2) r = fv1[u];
        else if constexpr (D == 3) r = fv2[u];
        else r = fv3[u];
        if constexpr (F::RL > 0) {
          if constexpr (D == 2) powmul<F::RL>(r, srcat(SL, tailL, u));
          else                  powmul<F::RL>(r, srcat(SLm1, tailLm1, u));
        }
        if constexpr (F::R1 > 0) powmul<F::R1>(r, srcat(S1, tail1, u));
        if constexpr (F::R2 > 0) powmul<F::R2>(r, srcat(S2, tail2, u));
        if constexpr (F::R3 > 0) powmul<F::R3>(r, srcat(S3, tail3, u));
        MAX4(racc, r);
      }
    }

    // ---- SLm1 rotation (before SL is overwritten), then leaf update ----
    if constexpr (NEEDM1) {
#pragma unroll
      for (int u = 0; u < 4; ++u) SLm1[u] = SL[u];
      tailLm1 = tailL;
    }
    run_update(loL, q + 0, SL, tailL);

    if constexpr (D == 1) {  // root for band i (needs fresh SL)
#pragma unroll
      for (int u = 0; u < 4; ++u) {
        float4 r = fv0[u];
        powmul<F::RL>(r, srcat(SL, tailL, u));
        MAX4(racc, r);
      }
    }

    // ---- generation rotations ----
    if constexpr (D >= 4) {
#pragma unroll
      for (int u = 0; u < 4; ++u) fv3[u] = fv2[u];
    }
    if constexpr (D >= 3) {
#pragma unroll
      for (int u = 0; u < 4; ++u) fv2[u] = fv1[u];
    }
    if constexpr (D >= 2) {
#pragma unroll
      for (int u = 0; u < 4; ++u) fv1[u] = fv0[u];
    }
#pragma unroll
    for (int u = 0; u < 4; ++u) X[u] = T[u];
  }

  float m = fmaxf(fmaxf(racc.x, racc.y), fmaxf(racc.z, racc.w));
#pragma unroll
  for (int d = 1; d < 64; d <<= 1) m = fmaxf(m, __shfl_xor(m, d));
  if (lane == 0) *outp = expf(asum) * m - 1.f;
}

__global__ __launch_bounds__(64) void fis_kernel(const float* __restrict__ x,
                                                 const float* __restrict__ alphas,
                                                 float* __restrict__ out,
                                                 Cls cls) {
  const int lane = threadIdx.x;
  const int blk  = blockIdx.x;
  const int t    = blk >> 7;     // blocks 128 apart share x-plane -> same XCD
  const int bc   = blk & 127;
  const int c    = bc & (CC - 1);
  const int b    = bc >> 4;

  const float* __restrict__ xp = x + (size_t)bc * (HH * WW);

  float asum = 0.f;
#pragma unroll
  for (int i = 0; i < NNODES; ++i) asum += alphas[(t * NNODES + i) * CC + c];

  const int   w0   = lane * 4;
  const float mask = (w0 < WW) ? 1.0f : 0.0f;
  const float* __restrict__ cp = xp + ((w0 < WW) ? w0 : (WW - 4));
  float* outp = out + ((size_t)b * NTREES + t) * CC + c;

  switch (cls.v[t]) {
    case 1: run_tree<1>(cp, mask, asum, outp, lane); break;
    case 2: run_tree<2>(cp, mask, asum, outp, lane); break;
    case 3: run_tree<3>(cp, mask, asum, outp, lane); break;
    case 4: run_tree<4>(cp, mask, asum, outp, lane); break;
    case 5: run_tree<5>(cp, mask, asum, outp, lane); break;
    case 6: run_tree<6>(cp, mask, asum, outp, lane); break;
    case 7: run_tree<7>(cp, mask, asum, outp, lane); break;
    case 8: run_tree<8>(cp, mask, asum, outp, lane); break;
    case 9: run_tree<9>(cp, mask, asum, outp, lane); break;
    default: break;
  }
}

extern "C" void kernel_launch(void* const* d_in, const int* in_sizes, int n_in,
                              void* d_out, int out_size, void* d_ws, size_t ws_size,
                              hipStream_t stream) {
  const float* x      = (const float*)d_in[0];
  const float* alphas = (const float*)d_in[1];
  float* out          = (float*)d_out;

  Forest f;
  nprng::make_forest(f);  // deterministic; same every call (graph-capture safe)

  Cls cls;
  for (int t = 0; t < NTREES; ++t)
    cls.v[t] = classify_tree(&f.par[t * NNODES]);

  dim3 grid(BB * CC * NTREES);  // 1024 single-wave blocks
  dim3 block(64);
  hipLaunchKernelGGL(fis_kernel, grid, block, 0, stream, x, alphas, out, cls);
}